// Round 6
// baseline (24.550 us; speedup 1.0000x reference)
//
#include <hip/hip_runtime.h>

#define N 2048
#define BATCH 32
#define BLOCK 256
#define SUBS 16                    // threads cooperating per query-pair
#define RQ 2                       // queries (i's) per thread
#define I_PER_BLOCK ((BLOCK / SUBS) * RQ)   // 32
#define SLICES (N / I_PER_BLOCK)            // 64 blocks per batch row
#define J4_PER_THREAD (N / 4 / SUBS)        // 32 float4 per thread

typedef float v2f __attribute__((ext_vector_type(2)));

// Hybrid exp: per float4 of j's, elems {x,y} computed as (e^{u})^8 with
// deg-4 Taylor on u = xi*xj/128 (|u|<~0.2, rel err ~2e-5) on the packed-f32
// VALU pipe; elems {z,w} via v_exp_f32 on the trans pipe. Balances the two
// pipes (~6 us each) instead of trans-bound 13.7 us. No max-subtraction
// (args bounded, scale cancels in num/den — validated R3-R5).
__global__ __launch_bounds__(BLOCK, 8) void rank1_attn_kernel(
    const float* __restrict__ x, float* __restrict__ y) {
    __shared__ float sx[N];

    const int b     = blockIdx.x / SLICES;
    const int slice = blockIdx.x % SLICES;
    const int tid   = threadIdx.x;

    const float* xb = x + b * N;

    // ---- stage row into LDS (coalesced float4) ----
    const float4* xb4 = reinterpret_cast<const float4*>(xb);
    float4* sx4 = reinterpret_cast<float4*>(sx);
#pragma unroll
    for (int k = 0; k < 2; ++k) sx4[tid + k * BLOCK] = xb4[tid + k * BLOCK];
    __syncthreads();

    const int group = tid / SUBS;       // 0..15
    const int sub   = tid % SUBS;       // 0..15
    const int i0    = slice * I_PER_BLOCK + group * RQ;

    const float C2 = 1.4426950408889634f / 16.0f;   // log2(e)/16  (exp path)
    v2f tl2[RQ];   // exp-path per-i constant (log2 domain)
    v2f t8[RQ];    // poly-path per-i constant xi/128 (natural domain /8)
#pragma unroll
    for (int r = 0; r < RQ; ++r) {
        const float xi = sx[i0 + r];
        const float a  = xi * C2;
        const float u8 = xi * (1.0f / 128.0f);
        tl2[r] = (v2f){a, a};
        t8[r]  = (v2f){u8, u8};
    }

    v2f denP[RQ], numP[RQ], denE[RQ], numE[RQ];
#pragma unroll
    for (int r = 0; r < RQ; ++r) {
        denP[r] = (v2f){0.f, 0.f}; numP[r] = (v2f){0.f, 0.f};
        denE[r] = (v2f){0.f, 0.f}; numE[r] = (v2f){0.f, 0.f};
    }

    const v2f c4 = {1.f / 24.f, 1.f / 24.f};
    const v2f c3 = {1.f / 6.f,  1.f / 6.f};
    const v2f c2 = {0.5f, 0.5f};
    const v2f c1 = {1.0f, 1.0f};

    const float4* s4 = reinterpret_cast<const float4*>(sx);
#pragma unroll 4
    for (int jj = 0; jj < J4_PER_THREAD; ++jj) {
        float4 v = s4[jj * SUBS + sub];
        v2f v01 = {v.x, v.y};
        v2f v23 = {v.z, v.w};
#pragma unroll
        for (int r = 0; r < RQ; ++r) {
            // --- poly path (VALU pipe): p8 = e^{xi*xj/16} ---
            v2f u = t8[r] * v01;               // v_pk_mul
            v2f p = u * c4 + c3;               // v_pk_fma chain
            p = p * u + c2;
            p = p * u + c1;
            p = p * u + c1;
            p = p * p; p = p * p; p = p * p;   // ^8
            denP[r] += p;
            numP[r] = p * v01 + numP[r];
            // --- exp path (trans pipe) ---
            v2f a = tl2[r] * v23;
            v2f e;
            e.x = __builtin_amdgcn_exp2f(a.x);
            e.y = __builtin_amdgcn_exp2f(a.y);
            denE[r] += e;
            numE[r] = e * v23 + numE[r];
        }
    }

#pragma unroll
    for (int r = 0; r < RQ; ++r) {
        float den = (denP[r].x + denP[r].y) + (denE[r].x + denE[r].y);
        float num = (numP[r].x + numP[r].y) + (numE[r].x + numE[r].y);
        // reduce across the 16 cooperating lanes
#pragma unroll
        for (int off = 1; off < SUBS; off <<= 1) {
            den += __shfl_xor(den, off);
            num += __shfl_xor(num, off);
        }
        if (sub == 0) y[b * N + i0 + r] = num / den;
    }
}

extern "C" void kernel_launch(void* const* d_in, const int* in_sizes, int n_in,
                              void* d_out, int out_size, void* d_ws, size_t ws_size,
                              hipStream_t stream) {
    const float* x = (const float*)d_in[0];
    float* y = (float*)d_out;
    dim3 grid(BATCH * SLICES);
    dim3 block(BLOCK);
    rank1_attn_kernel<<<grid, block, 0, stream>>>(x, y);
}